// Round 12
// baseline (235.319 us; speedup 1.0000x reference)
//
#include <hip/hip_runtime.h>
#include <math.h>

#define BATCH 4
#define SEQ 2048
#define DMODEL 1024
#define NHEAD 16
#define DHEAD 64
#define MTOT (BATCH * SEQ)   /* 8192 */
#define LN_EPS 1e-5f

typedef float f4 __attribute__((ext_vector_type(4)));
typedef float f32x4 __attribute__((ext_vector_type(4)));
typedef __bf16 bf16_t;
typedef __bf16 bf16x8 __attribute__((ext_vector_type(8)));
typedef __bf16 bf16x4 __attribute__((ext_vector_type(4)));

// async global->LDS, 16B per lane; dest = wave-uniform base + lane*16
__device__ __forceinline__ void gload_lds16(const bf16_t* g, bf16_t* l) {
    __builtin_amdgcn_global_load_lds(
        (const __attribute__((address_space(1))) void*)g,
        (__attribute__((address_space(3))) void*)l, 16, 0, 0);
}

// ---------------------------------------------------------------------------
// fp32 -> bf16 elementwise (n4 = count of float4 groups)
// ---------------------------------------------------------------------------
__global__ __launch_bounds__(256) void cvt_bf16(
    const float* __restrict__ x, bf16_t* __restrict__ y, int n4)
{
    for (int i = blockIdx.x * 256 + threadIdx.x; i < n4; i += gridDim.x * 256) {
        f4 v = *(const f4*)&x[(size_t)i * 4];
        bf16x4 o;
        o[0] = (bf16_t)v[0]; o[1] = (bf16_t)v[1];
        o[2] = (bf16_t)v[2]; o[3] = (bf16_t)v[3];
        *(bf16x4*)&y[(size_t)i * 4] = o;
    }
}

// ---------------------------------------------------------------------------
// 4x W[k][n] fp32 -> Wt[n][k] bf16, fused into one launch (z selects matrix;
// outputs contiguous at Wt + z*1024*1024)
// ---------------------------------------------------------------------------
__global__ __launch_bounds__(256) void wtrans4(
    const float* __restrict__ W0, const float* __restrict__ W1,
    const float* __restrict__ W2, const float* __restrict__ W3,
    bf16_t* __restrict__ Wt)
{
    __shared__ float tile[32][33];
    const int z = blockIdx.z;
    const float* W = (z == 0) ? W0 : (z == 1) ? W1 : (z == 2) ? W2 : W3;
    bf16_t* dst = Wt + (size_t)z * DMODEL * DMODEL;
    const int n0 = blockIdx.x * 32, k0 = blockIdx.y * 32;
    const int c = threadIdx.x & 31, rr = threadIdx.x >> 5;   // 8 rows/pass
#pragma unroll
    for (int i = 0; i < 32; i += 8)
        tile[rr + i][c] = W[(size_t)(k0 + rr + i) * DMODEL + n0 + c];
    __syncthreads();
#pragma unroll
    for (int i = 0; i < 32; i += 8)
        dst[(size_t)(n0 + rr + i) * DMODEL + k0 + c] = (bf16_t)tile[c][rr + i];
}

// ---------------------------------------------------------------------------
// bf16 MFMA GEMM, double-buffered + counted vmcnt (no drain in loop).
// 128x128 tile, BK=32, 4 waves (2x2), 16x16x32 MFMA, global_load_lds(16B).
// FUSED3=1: Bt = [3072][1024] (Wq|Wk|Wv rows), C = 3 contiguous bf16 buffers.
// ---------------------------------------------------------------------------
template<int OUT_BF16, int FUSED3>
__global__ __launch_bounds__(256) void gemm_mfma(
    const bf16_t* __restrict__ A, const bf16_t* __restrict__ Bt,
    const float* __restrict__ bias0, const float* __restrict__ bias1,
    const float* __restrict__ bias2, void* __restrict__ Cout)
{
    __shared__ bf16_t As[2][4096];
    __shared__ bf16_t Bs[2][4096];
    const int t = threadIdx.x;
    const int w = t >> 6, lane = t & 63;
    const int r16 = lane & 15, g = lane >> 4;

    // XCD swizzle (bijective): xc = flat&7 gets contiguous 8 m-tiles
    const int flat = blockIdx.x;
    const int xc = flat & 7;
    const int t2 = flat >> 3;
    int nx, my;
    if (FUSED3) { nx = t2 % 24; my = 8 * xc + t2 / 24; }   // 1536 blocks
    else        { nx = t2 & 7;  my = 8 * xc + (t2 >> 3); } // 512 blocks
    const int m0 = my * 128, n0 = nx * 128;
    const int wr = w >> 1, wc = w & 1;

    // staging: issue r in {0,1}: dest byte y = r*4096 + w*1024 + lane*16
    const int y0 = w * 1024 + lane * 16;
    const int y1 = y0 + 4096;
    const int row0 = y0 >> 6, row1 = y1 >> 6;
    const int sl0 = ((y0 >> 4) & 3) ^ ((row0 >> 1) & 3);
    const int sl1 = ((y1 >> 4) & 3) ^ ((row1 >> 1) & 3);
    const bf16_t* a0 = A + (size_t)(m0 + row0) * DMODEL + sl0 * 8;
    const bf16_t* a1 = A + (size_t)(m0 + row1) * DMODEL + sl1 * 8;
    const bf16_t* b0 = Bt + (size_t)(n0 + row0) * DMODEL + sl0 * 8;
    const bf16_t* b1 = Bt + (size_t)(n0 + row1) * DMODEL + sl1 * 8;

    // fragment read offsets (elements), swizzled
    int aoff[4], boff[4];
#pragma unroll
    for (int i = 0; i < 4; ++i) {
        int ar = wr * 64 + i * 16 + r16;
        int al = ar * 64 + g * 16;
        al ^= ((ar >> 1) & 3) << 4;
        aoff[i] = al >> 1;
        int br = wc * 64 + i * 16 + r16;
        int bl = br * 64 + g * 16;
        bl ^= ((br >> 1) & 3) << 4;
        boff[i] = bl >> 1;
    }

    // bias preload (before K-loop: FIFO-drains with prologue stage)
    const int sel   = FUSED3 ? (n0 >> 10) : 0;
    const int c1b   = FUSED3 ? (n0 & 1023) : n0;
    const float* bp = (!FUSED3 || sel == 0) ? bias0 : (sel == 1) ? bias1 : bias2;
    float bvj[4];
#pragma unroll
    for (int j = 0; j < 4; ++j)
        bvj[j] = bp[c1b + wc * 64 + j * 16 + r16];

    const f32x4 z4 = {0.f, 0.f, 0.f, 0.f};
    f32x4 acc[4][4];
#pragma unroll
    for (int i = 0; i < 4; ++i)
#pragma unroll
        for (int j = 0; j < 4; ++j) acc[i][j] = z4;

#define STAGE(buf, kk) do { \
        gload_lds16(a0 + (kk), &As[buf][w * 512]); \
        gload_lds16(a1 + (kk), &As[buf][2048 + w * 512]); \
        gload_lds16(b0 + (kk), &Bs[buf][w * 512]); \
        gload_lds16(b1 + (kk), &Bs[buf][2048 + w * 512]); \
    } while (0)

    STAGE(0, 0);   // prologue
    const int NKT = DMODEL / 32;       // 32
    for (int kt = 0; kt < NKT; ++kt) {
        const int cur = kt & 1;
        if (kt + 1 < NKT) {
            STAGE(cur ^ 1, (kt + 1) * 32);                  // prefetch t+1
            asm volatile("s_waitcnt vmcnt(4)" ::: "memory"); // tile t landed
        } else {
            asm volatile("s_waitcnt vmcnt(0)" ::: "memory");
        }
        __builtin_amdgcn_s_barrier();    // B1: tile t visible to all waves

        bf16x8 af[4], bfr[4];
#pragma unroll
        for (int i = 0; i < 4; ++i) af[i] = *(const bf16x8*)&As[cur][aoff[i]];
#pragma unroll
        for (int j = 0; j < 4; ++j) bfr[j] = *(const bf16x8*)&Bs[cur][boff[j]];
#pragma unroll
        for (int i = 0; i < 4; ++i)
#pragma unroll
            for (int j = 0; j < 4; ++j)
                acc[i][j] = __builtin_amdgcn_mfma_f32_16x16x32_bf16(
                    af[i], bfr[j], acc[i][j], 0, 0, 0);

        asm volatile("s_waitcnt lgkmcnt(0)" ::: "memory");
        __builtin_amdgcn_s_barrier();    // B2: reads done before next STAGE
    }
#undef STAGE

    // epilogue: D row = (lane>>4)*4 + reg, col = lane&15  (m89-verified)
#pragma unroll
    for (int j = 0; j < 4; ++j) {
        const int colw = (FUSED3 ? c1b : n0) + wc * 64 + j * 16 + r16;
        const float bv = bvj[j];
#pragma unroll
        for (int i = 0; i < 4; ++i) {
            const int rbase = m0 + wr * 64 + i * 16 + g * 4;
#pragma unroll
            for (int rr = 0; rr < 4; ++rr) {
                float vv = acc[i][j][rr] + bv;
                if (OUT_BF16)
                    ((bf16_t*)Cout)[(size_t)sel * (MTOT * DMODEL) +
                                    (size_t)(rbase + rr) * DMODEL + colw] = (bf16_t)vv;
                else
                    ((float*)Cout)[(size_t)(rbase + rr) * DMODEL + colw] = vv;
            }
        }
    }
}

// ---------------------------------------------------------------------------
// MFMA flash attention, 4 waves x 256 threads, 32 q-rows/wave (QBLK=128),
// KVBLK=128. LDS-traffic-optimized: each K-fragment and V-fragment ds_read
// feeds TWO q-groups (A: rows 32w+r16, B: rows 32w+16+r16) -> DS bytes per
// FLOP halved vs the 8-wave version (DS pipe was the measured wall: 73.4M
// cyc model == 114us wall).
// Fixed-shift softmax (exact; see R11): p = exp2(s*C2 - M2), per-lane
// denominator partials, one cross-lane reduce after the loop.
// LDS 64KB: Ks dbuf 32K + Vt 16K + Ps 16K -> 2 blocks/CU (128KB, slack).
// ---------------------------------------------------------------------------
__global__ __launch_bounds__(256, 2) void flash_mfma(
    const bf16_t* __restrict__ qg, const bf16_t* __restrict__ kg,
    const bf16_t* __restrict__ vg, bf16_t* __restrict__ ctx)
{
    __shared__ bf16_t Ks[2][128 * 64];  // [key][dim], byte ^= (key&7)<<4
    __shared__ bf16_t Vt[2][64 * 64];   // [half][dim][key], unit ^= dim&7
    __shared__ bf16_t Ps[128 * 64];     // [q][key-half], reused per half

    const int t = threadIdx.x;
    const int w = t >> 6, lane = t & 63;   // w in 0..3
    const int r16 = lane & 15, g = lane >> 4;
    const int g4 = g * 4;

    // XCD swizzle: flat = xc + 8*(qt + 16*(gid>>3)); gid&7 = xc
    const int flat = blockIdx.x;
    const int xc  = flat & 7;
    const int kk  = flat >> 3;                  // 0..127
    const int gid = ((kk >> 4) << 3) | xc;      // 0..63 = (b,h)
    const int qt  = kk & 15;
    const int b = gid >> 4, h = gid & 15;
    const int q0 = qt * 128;

    // Q fragments: group A rows q0+32w+r16, group B rows q0+32w+16+r16
    bf16x8 qfA0, qfA1, qfB0, qfB1;
    {
        const bf16_t* qrA = qg + (size_t)(b * SEQ + q0 + 32 * w + r16) * DMODEL + h * DHEAD;
        const bf16_t* qrB = qrA + (size_t)16 * DMODEL;
        qfA0 = *(const bf16x8*)&qrA[g * 8];
        qfA1 = *(const bf16x8*)&qrA[32 + g * 8];
        qfB0 = *(const bf16x8*)&qrB[g * 8];
        qfB1 = *(const bf16x8*)&qrB[32 + g * 8];
    }

    // K staging: 4 issues/thread; dest byte y = r*4096 + w*1024 + lane*16
    const bf16_t* kb[4];
    int kdo[4];
#pragma unroll
    for (int r = 0; r < 4; ++r) {
        const int y = r * 4096 + w * 1024 + lane * 16;
        const int krow = y >> 7;                        // 0..127
        const int kslot = ((y >> 4) & 7) ^ (krow & 7);  // pre-swizzled src col
        kb[r] = kg + (size_t)(b * SEQ + krow) * DMODEL + h * DHEAD + kslot * 8;
        kdo[r] = r * 2048 + w * 512;                    // elem offset in Ks[b]
    }

    // V staging: keys lane (half0) / 64+lane (half1), dims [w*16, w*16+16)
    const bf16_t* vb0 = vg + (size_t)(b * SEQ + lane) * DMODEL + h * DHEAD + w * 16;
    const bf16_t* vb1 = vb0 + (size_t)64 * DMODEL;

    // K fragment base offsets (elems); key = nj*16 + r16 -> + nj*1024
    const int klin0 = ((r16 * 128 + g * 16) ^ ((r16 & 7) << 4)) >> 1;
    const int klin1 = ((r16 * 128 + 64 + g * 16) ^ ((r16 & 7) << 4)) >> 1;

    const int lu = lane >> 3, l7 = lane & 7;   // V-write unit/offset
    const int qs = r16 & 7;                    // (32w+r16)&7 == (32w+16+r16)&7

    const f32x4 z4 = {0.f, 0.f, 0.f, 0.f};
    float l2A = 0.f, l2B = 0.f;        // per-lane denominator partials
    f32x4 oA[4], oB[4];
#pragma unroll
    for (int i = 0; i < 4; ++i) { oA[i] = z4; oB[i] = z4; }

    const float C2 = 0.1803368801f;    // (1/8) * log2(e)
    const float M2 = 17.31234049f;     // 12 * log2(e): fixed softmax shift

    // prologue: stage tile 0 (V loads issued after K gloads -> FIFO drain)
#pragma unroll
    for (int r = 0; r < 4; ++r) gload_lds16(kb[r], &Ks[0][kdo[r]]);
    bf16x8 vc0a = *(const bf16x8*)&vb0[0];
    bf16x8 vc0b = *(const bf16x8*)&vb0[8];
    bf16x8 vc1a = *(const bf16x8*)&vb1[0];
    bf16x8 vc1b = *(const bf16x8*)&vb1[8];
    bf16x8 vn0a = vc0a, vn0b = vc0b, vn1a = vc1a, vn1b = vc1b;

    const int NT = SEQ / 128;          // 16
    for (int it = 0; it < NT; ++it) {
        const int cur = it & 1;
        const int kv0 = it * 128;

        // 1. Vt write (vmcnt wait on vcur drains K(t) gloads too)
        //    dims d = w*16+e (e 0..15); d&7 == e&7
#pragma unroll
        for (int e = 0; e < 8; ++e) {
            const int dst0 = (w * 16 + e) * 64 + (((lu ^ e) << 3) | l7);
            const int dst1 = (w * 16 + 8 + e) * 64 + (((lu ^ e) << 3) | l7);
            Vt[0][dst0] = vc0a[e];
            Vt[1][dst0] = vc1a[e];
            Vt[0][dst1] = vc0b[e];
            Vt[1][dst1] = vc1b[e];
        }

        // 2. B1
        asm volatile("s_waitcnt lgkmcnt(0)" ::: "memory");
        __builtin_amdgcn_s_barrier();

        // 3. prefetch tile t+1 (stays in flight across compute)
        if (it + 1 < NT) {
#pragma unroll
            for (int r = 0; r < 4; ++r)
                gload_lds16(kb[r] + (size_t)(kv0 + 128) * DMODEL, &Ks[cur ^ 1][kdo[r]]);
            const bf16_t* v0 = vb0 + (size_t)(kv0 + 128) * DMODEL;
            const bf16_t* v1 = vb1 + (size_t)(kv0 + 128) * DMODEL;
            vn0a = *(const bf16x8*)&v0[0];
            vn0b = *(const bf16x8*)&v0[8];
            vn1a = *(const bf16x8*)&v1[0];
            vn1b = *(const bf16x8*)&v1[8];
        }

        // 4. S^T = K Q^T for both q-groups; each kf pair feeds 4 MFMAs
        f32x4 sA[8], sB[8];
        __builtin_amdgcn_s_setprio(1);
#pragma unroll
        for (int nj = 0; nj < 8; ++nj) {
            bf16x8 kf0 = *(const bf16x8*)&Ks[cur][klin0 + nj * 1024];
            bf16x8 kf1 = *(const bf16x8*)&Ks[cur][klin1 + nj * 1024];
            sA[nj] = __builtin_amdgcn_mfma_f32_16x16x32_bf16(kf0, qfA0, z4, 0, 0, 0);
            sA[nj] = __builtin_amdgcn_mfma_f32_16x16x32_bf16(kf1, qfA1, sA[nj], 0, 0, 0);
            sB[nj] = __builtin_amdgcn_mfma_f32_16x16x32_bf16(kf0, qfB0, z4, 0, 0, 0);
            sB[nj] = __builtin_amdgcn_mfma_f32_16x16x32_bf16(kf1, qfB1, sB[nj], 0, 0, 0);
        }
        __builtin_amdgcn_s_setprio(0);

        // 5. two {exp, pack, PV} halves; vf reads shared by both q-groups
#pragma unroll
        for (int half = 0; half < 2; ++half) {
            const int nb = half * 4;
            const int qrA = 32 * w + r16;
            const int qrB = qrA + 16;

            float pA[4][4], pB[4][4];
            float rsA = 0.f, rsB = 0.f;
#pragma unroll
            for (int j = 0; j < 4; ++j)
#pragma unroll
                for (int rr = 0; rr < 4; ++rr) {
                    pA[j][rr] = __builtin_amdgcn_exp2f(sA[nb + j][rr] * C2 - M2);
                    rsA += pA[j][rr];
                    pB[j][rr] = __builtin_amdgcn_exp2f(sB[nb + j][rr] * C2 - M2);
                    rsB += pB[j][rr];
                }
            l2A += rsA;
            l2B += rsB;

            // Ps pack (wave-local rows; WAR vs prev half's reads is same-wave
            // in-order DS)
#pragma unroll
            for (int j = 0; j < 4; ++j) {
                bf16x4 pkA, pkB;
                pkA[0] = (bf16_t)pA[j][0]; pkA[1] = (bf16_t)pA[j][1];
                pkA[2] = (bf16_t)pA[j][2]; pkA[3] = (bf16_t)pA[j][3];
                pkB[0] = (bf16_t)pB[j][0]; pkB[1] = (bf16_t)pB[j][1];
                pkB[2] = (bf16_t)pB[j][2]; pkB[3] = (bf16_t)pB[j][3];
                const int u = ((((2 * j + (g >> 1)) ^ qs) << 3) | ((g & 1) << 2));
                *(bf16x4*)&Ps[qrA * 64 + u] = pkA;
                *(bf16x4*)&Ps[qrB * 64 + u] = pkB;
            }
            asm volatile("s_waitcnt lgkmcnt(0)" ::: "memory");
            bf16x8 pfA0 = *(const bf16x8*)&Ps[qrA * 64 + ((g ^ qs) << 3)];
            bf16x8 pfA1 = *(const bf16x8*)&Ps[qrA * 64 + (((4 + g) ^ qs) << 3)];
            bf16x8 pfB0 = *(const bf16x8*)&Ps[qrB * 64 + ((g ^ qs) << 3)];
            bf16x8 pfB1 = *(const bf16x8*)&Ps[qrB * 64 + (((4 + g) ^ qs) << 3)];

            __builtin_amdgcn_s_setprio(1);
#pragma unroll
            for (int dj = 0; dj < 4; ++dj) {
                const int d = dj * 16 + r16;
                bf16x8 vf0 = *(const bf16x8*)&Vt[half][d * 64 + ((g ^ qs) << 3)];
                bf16x8 vf1 = *(const bf16x8*)&Vt[half][d * 64 + (((4 + g) ^ qs) << 3)];
                oA[dj] = __builtin_amdgcn_mfma_f32_16x16x32_bf16(pfA0, vf0, oA[dj], 0, 0, 0);
                oA[dj] = __builtin_amdgcn_mfma_f32_16x16x32_bf16(pfA1, vf1, oA[dj], 0, 0, 0);
                oB[dj] = __builtin_amdgcn_mfma_f32_16x16x32_bf16(pfB0, vf0, oB[dj], 0, 0, 0);
                oB[dj] = __builtin_amdgcn_mfma_f32_16x16x32_bf16(pfB1, vf1, oB[dj], 0, 0, 0);
            }
            __builtin_amdgcn_s_setprio(0);
        }

        // 6. B2 (raw barrier; vmem prefetch stays in flight)
        asm volatile("s_waitcnt lgkmcnt(0)" ::: "memory");
        __builtin_amdgcn_s_barrier();

        vc0a = vn0a; vc0b = vn0b; vc1a = vn1a; vc1b = vn1b;
    }

    // final denominators: sum the 4 g-lane partials of each q-row (once)
    l2A += __shfl_xor(l2A, 16);
    l2A += __shfl_xor(l2A, 32);
    l2B += __shfl_xor(l2B, 16);
    l2B += __shfl_xor(l2B, 32);

    // write context (bf16): oA rows q = 32w+g4+rr, oB rows +16
#pragma unroll
    for (int rr = 0; rr < 4; ++rr) {
        const float invA = 1.0f / __shfl(l2A, g4 + rr, 16);
        const float invB = 1.0f / __shfl(l2B, g4 + rr, 16);
        const size_t rbA =
            (size_t)(b * SEQ + q0 + 32 * w + g4 + rr) * DMODEL + h * DHEAD;
        const size_t rbB = rbA + (size_t)16 * DMODEL;
#pragma unroll
        for (int dj = 0; dj < 4; ++dj) {
            ctx[rbA + dj * 16 + r16] = (bf16_t)(oA[dj][rr] * invA);
            ctx[rbB + dj * 16 + r16] = (bf16_t)(oB[dj][rr] * invB);
        }
    }
}

// ---------------------------------------------------------------------------
// out = LayerNorm(x + res) * g + b, rows of 1024. x is bf16, res fp32.
// ---------------------------------------------------------------------------
__global__ __launch_bounds__(256) void ln_residual(
    const bf16_t* __restrict__ x, const float* __restrict__ res,
    const float* __restrict__ g, const float* __restrict__ bb,
    float* __restrict__ out)
{
    const int row = blockIdx.x;
    const int t = threadIdx.x;
    bf16x4 xv = *(const bf16x4*)&x[(size_t)row * DMODEL + t * 4];
    f4 rv = *(const f4*)&res[(size_t)row * DMODEL + t * 4];
    f4 v;
#pragma unroll
    for (int u = 0; u < 4; ++u) v[u] = (float)xv[u] + rv[u];

    float s = 0.f, s2 = 0.f;
#pragma unroll
    for (int u = 0; u < 4; ++u) { s += v[u]; s2 += v[u] * v[u]; }
#pragma unroll
    for (int off = 1; off < 64; off <<= 1) {
        s  += __shfl_xor(s, off);
        s2 += __shfl_xor(s2, off);
    }
    __shared__ float red[2][4];
    const int wid = t >> 6, lane = t & 63;
    if (lane == 0) { red[0][wid] = s; red[1][wid] = s2; }
    __syncthreads();
    s  = red[0][0] + red[0][1] + red[0][2] + red[0][3];
    s2 = red[1][0] + red[1][1] + red[1][2] + red[1][3];

    const float mean = s * (1.0f / DMODEL);
    const float var  = s2 * (1.0f / DMODEL) - mean * mean;
    const float rstd = rsqrtf(var + LN_EPS);

    f4 gv = *(const f4*)&g[t * 4];
    f4 bv = *(const f4*)&bb[t * 4];
    f4 ov;
#pragma unroll
    for (int u = 0; u < 4; ++u) ov[u] = (v[u] - mean) * rstd * gv[u] + bv[u];
    *(f4*)&out[(size_t)row * DMODEL + t * 4] = ov;
}

// ---------------------------------------------------------------------------
extern "C" void kernel_launch(void* const* d_in, const int* in_sizes, int n_in,
                              void* d_out, int out_size, void* d_ws, size_t ws_size,
                              hipStream_t stream)
{
    const float* Q   = (const float*)d_in[0];
    const float* Wq  = (const float*)d_in[1];
    const float* bq  = (const float*)d_in[2];
    const float* Wk  = (const float*)d_in[3];
    const float* bk  = (const float*)d_in[4];
    const float* Wv  = (const float*)d_in[5];
    const float* bv  = (const float*)d_in[6];
    const float* Wo  = (const float*)d_in[7];
    const float* bo  = (const float*)d_in[8];
    const float* lng = (const float*)d_in[9];
    const float* lnb = (const float*)d_in[10];

    char* wsb = (char*)d_ws;
    // 0..16M: Qbf | 16..32M: q/ctx | 32..48M: k | 48..64M: v (q,k,v contiguous)
    // 32..48M (after attn): attn_out bf16 | 64..72M: Wqt|Wkt|Wvt|Wot contiguous
    bf16_t* Qbf  = (bf16_t*)(wsb);
    bf16_t* qb   = (bf16_t*)(wsb + (size_t)(16 << 20));
    bf16_t* kb   = (bf16_t*)(wsb + (size_t)(32 << 20));
    bf16_t* vbuf = (bf16_t*)(wsb + (size_t)(48 << 20));
    bf16_t* aob  = (bf16_t*)(wsb + (size_t)(32 << 20));
    bf16_t* Wqt  = (bf16_t*)(wsb + (size_t)(64 << 20));   // [3072][1024] fused
    bf16_t* Wot  = (bf16_t*)(wsb + (size_t)(70 << 20));

    cvt_bf16<<<2048, 256, 0, stream>>>(Q, Qbf, MTOT * DMODEL / 4);
    wtrans4<<<dim3(32, 32, 4), 256, 0, stream>>>(Wq, Wk, Wv, Wo, Wqt);

    // fused QKV projection: N=3072, outputs qb|kb|vbuf (contiguous)
    gemm_mfma<1, 1><<<24 * 64, 256, 0, stream>>>(Qbf, Wqt, bq, bk, bv, qb);

    const int agrid = (SEQ / 128) * NHEAD * BATCH;     // 1024, XCD-swizzled
    flash_mfma<<<agrid, 256, 0, stream>>>(qb, kb, vbuf, qb);  // ctx aliases q

    gemm_mfma<1, 0><<<8 * 64, 256, 0, stream>>>(qb, Wot, bo, bo, bo, aob);

    ln_residual<<<MTOT, 256, 0, stream>>>(aob, Q, lng, lnb, (float*)d_out);
}

// Round 13
// 219.437 us; speedup vs baseline: 1.0724x; 1.0724x over previous
//
#include <hip/hip_runtime.h>
#include <math.h>

#define BATCH 4
#define SEQ 2048
#define DMODEL 1024
#define NHEAD 16
#define DHEAD 64
#define MTOT (BATCH * SEQ)   /* 8192 */
#define LN_EPS 1e-5f

typedef float f4 __attribute__((ext_vector_type(4)));
typedef float f32x4 __attribute__((ext_vector_type(4)));
typedef __bf16 bf16_t;
typedef __bf16 bf16x8 __attribute__((ext_vector_type(8)));
typedef __bf16 bf16x4 __attribute__((ext_vector_type(4)));

// async global->LDS, 16B per lane; dest = wave-uniform base + lane*16
__device__ __forceinline__ void gload_lds16(const bf16_t* g, bf16_t* l) {
    __builtin_amdgcn_global_load_lds(
        (const __attribute__((address_space(1))) void*)g,
        (__attribute__((address_space(3))) void*)l, 16, 0, 0);
}

// ---------------------------------------------------------------------------
// fp32 -> bf16 elementwise (n4 = count of float4 groups)
// ---------------------------------------------------------------------------
__global__ __launch_bounds__(256) void cvt_bf16(
    const float* __restrict__ x, bf16_t* __restrict__ y, int n4)
{
    for (int i = blockIdx.x * 256 + threadIdx.x; i < n4; i += gridDim.x * 256) {
        f4 v = *(const f4*)&x[(size_t)i * 4];
        bf16x4 o;
        o[0] = (bf16_t)v[0]; o[1] = (bf16_t)v[1];
        o[2] = (bf16_t)v[2]; o[3] = (bf16_t)v[3];
        *(bf16x4*)&y[(size_t)i * 4] = o;
    }
}

// ---------------------------------------------------------------------------
// 4x W[k][n] fp32 -> Wt[n][k] bf16, fused into one launch (z selects matrix;
// outputs contiguous at Wt + z*1024*1024)
// ---------------------------------------------------------------------------
__global__ __launch_bounds__(256) void wtrans4(
    const float* __restrict__ W0, const float* __restrict__ W1,
    const float* __restrict__ W2, const float* __restrict__ W3,
    bf16_t* __restrict__ Wt)
{
    __shared__ float tile[32][33];
    const int z = blockIdx.z;
    const float* W = (z == 0) ? W0 : (z == 1) ? W1 : (z == 2) ? W2 : W3;
    bf16_t* dst = Wt + (size_t)z * DMODEL * DMODEL;
    const int n0 = blockIdx.x * 32, k0 = blockIdx.y * 32;
    const int c = threadIdx.x & 31, rr = threadIdx.x >> 5;   // 8 rows/pass
#pragma unroll
    for (int i = 0; i < 32; i += 8)
        tile[rr + i][c] = W[(size_t)(k0 + rr + i) * DMODEL + n0 + c];
    __syncthreads();
#pragma unroll
    for (int i = 0; i < 32; i += 8)
        dst[(size_t)(n0 + rr + i) * DMODEL + k0 + c] = (bf16_t)tile[c][rr + i];
}

// ---------------------------------------------------------------------------
// bf16 MFMA GEMM, double-buffered + counted vmcnt (no drain in loop).
// 128x128 tile, BK=32, 4 waves (2x2), 16x16x32 MFMA, global_load_lds(16B).
// FUSED3=1: Bt = [3072][1024] (Wq|Wk|Wv rows), C = 3 contiguous bf16 buffers.
// ---------------------------------------------------------------------------
template<int OUT_BF16, int FUSED3>
__global__ __launch_bounds__(256) void gemm_mfma(
    const bf16_t* __restrict__ A, const bf16_t* __restrict__ Bt,
    const float* __restrict__ bias0, const float* __restrict__ bias1,
    const float* __restrict__ bias2, void* __restrict__ Cout)
{
    __shared__ bf16_t As[2][4096];
    __shared__ bf16_t Bs[2][4096];
    const int t = threadIdx.x;
    const int w = t >> 6, lane = t & 63;
    const int r16 = lane & 15, g = lane >> 4;

    // XCD swizzle (bijective): xc = flat&7 gets contiguous 8 m-tiles
    const int flat = blockIdx.x;
    const int xc = flat & 7;
    const int t2 = flat >> 3;
    int nx, my;
    if (FUSED3) { nx = t2 % 24; my = 8 * xc + t2 / 24; }   // 1536 blocks
    else        { nx = t2 & 7;  my = 8 * xc + (t2 >> 3); } // 512 blocks
    const int m0 = my * 128, n0 = nx * 128;
    const int wr = w >> 1, wc = w & 1;

    // staging: issue r in {0,1}: dest byte y = r*4096 + w*1024 + lane*16
    const int y0 = w * 1024 + lane * 16;
    const int y1 = y0 + 4096;
    const int row0 = y0 >> 6, row1 = y1 >> 6;
    const int sl0 = ((y0 >> 4) & 3) ^ ((row0 >> 1) & 3);
    const int sl1 = ((y1 >> 4) & 3) ^ ((row1 >> 1) & 3);
    const bf16_t* a0 = A + (size_t)(m0 + row0) * DMODEL + sl0 * 8;
    const bf16_t* a1 = A + (size_t)(m0 + row1) * DMODEL + sl1 * 8;
    const bf16_t* b0 = Bt + (size_t)(n0 + row0) * DMODEL + sl0 * 8;
    const bf16_t* b1 = Bt + (size_t)(n0 + row1) * DMODEL + sl1 * 8;

    // fragment read offsets (elements), swizzled
    int aoff[4], boff[4];
#pragma unroll
    for (int i = 0; i < 4; ++i) {
        int ar = wr * 64 + i * 16 + r16;
        int al = ar * 64 + g * 16;
        al ^= ((ar >> 1) & 3) << 4;
        aoff[i] = al >> 1;
        int br = wc * 64 + i * 16 + r16;
        int bl = br * 64 + g * 16;
        bl ^= ((br >> 1) & 3) << 4;
        boff[i] = bl >> 1;
    }

    // bias preload (before K-loop: FIFO-drains with prologue stage)
    const int sel   = FUSED3 ? (n0 >> 10) : 0;
    const int c1b   = FUSED3 ? (n0 & 1023) : n0;
    const float* bp = (!FUSED3 || sel == 0) ? bias0 : (sel == 1) ? bias1 : bias2;
    float bvj[4];
#pragma unroll
    for (int j = 0; j < 4; ++j)
        bvj[j] = bp[c1b + wc * 64 + j * 16 + r16];

    const f32x4 z4 = {0.f, 0.f, 0.f, 0.f};
    f32x4 acc[4][4];
#pragma unroll
    for (int i = 0; i < 4; ++i)
#pragma unroll
        for (int j = 0; j < 4; ++j) acc[i][j] = z4;

#define STAGE(buf, kk) do { \
        gload_lds16(a0 + (kk), &As[buf][w * 512]); \
        gload_lds16(a1 + (kk), &As[buf][2048 + w * 512]); \
        gload_lds16(b0 + (kk), &Bs[buf][w * 512]); \
        gload_lds16(b1 + (kk), &Bs[buf][2048 + w * 512]); \
    } while (0)

    STAGE(0, 0);   // prologue
    const int NKT = DMODEL / 32;       // 32
    for (int kt = 0; kt < NKT; ++kt) {
        const int cur = kt & 1;
        if (kt + 1 < NKT) {
            STAGE(cur ^ 1, (kt + 1) * 32);                  // prefetch t+1
            asm volatile("s_waitcnt vmcnt(4)" ::: "memory"); // tile t landed
        } else {
            asm volatile("s_waitcnt vmcnt(0)" ::: "memory");
        }
        __builtin_amdgcn_s_barrier();    // B1: tile t visible to all waves

        bf16x8 af[4], bfr[4];
#pragma unroll
        for (int i = 0; i < 4; ++i) af[i] = *(const bf16x8*)&As[cur][aoff[i]];
#pragma unroll
        for (int j = 0; j < 4; ++j) bfr[j] = *(const bf16x8*)&Bs[cur][boff[j]];
#pragma unroll
        for (int i = 0; i < 4; ++i)
#pragma unroll
            for (int j = 0; j < 4; ++j)
                acc[i][j] = __builtin_amdgcn_mfma_f32_16x16x32_bf16(
                    af[i], bfr[j], acc[i][j], 0, 0, 0);

        asm volatile("s_waitcnt lgkmcnt(0)" ::: "memory");
        __builtin_amdgcn_s_barrier();    // B2: reads done before next STAGE
    }
#undef STAGE

    // epilogue: D row = (lane>>4)*4 + reg, col = lane&15  (m89-verified)
#pragma unroll
    for (int j = 0; j < 4; ++j) {
        const int colw = (FUSED3 ? c1b : n0) + wc * 64 + j * 16 + r16;
        const float bv = bvj[j];
#pragma unroll
        for (int i = 0; i < 4; ++i) {
            const int rbase = m0 + wr * 64 + i * 16 + g * 4;
#pragma unroll
            for (int rr = 0; rr < 4; ++rr) {
                float vv = acc[i][j][rr] + bv;
                if (OUT_BF16)
                    ((bf16_t*)Cout)[(size_t)sel * (MTOT * DMODEL) +
                                    (size_t)(rbase + rr) * DMODEL + colw] = (bf16_t)vv;
                else
                    ((float*)Cout)[(size_t)(rbase + rr) * DMODEL + colw] = vv;
            }
        }
    }
}

// ---------------------------------------------------------------------------
// MFMA flash attention, 8 waves x 512 threads, 32 q-rows/wave (QBLK=256),
// KVBLK=64. Combines R11's TLP (16 waves/CU) with R12's DS-sharing (each
// kf/vf ds_read feeds both q-groups A: rows 32w+r16, B: +16).
// Fixed-shift softmax (exact; R11): p = exp2(s*C2 - M2), per-lane partial
// denominators, one cross-lane reduce after the loop.
// LDS 56KB (Ks dbuf 16K + Vt 8K + Ps 32K) -> 2 blocks/CU (112K, slack).
// Swizzles: Ks byte ^= (key&7)<<4; Vt/Ps 8B-unit ^= row&7 (row&7 == r16&7
// for all q-rows and dims used -> constants unchanged from R8/R11).
// ---------------------------------------------------------------------------
__global__ __launch_bounds__(512, 4) void flash_mfma(
    const bf16_t* __restrict__ qg, const bf16_t* __restrict__ kg,
    const bf16_t* __restrict__ vg, bf16_t* __restrict__ ctx)
{
    __shared__ bf16_t Ks[2][64 * 64];   // [key][dim], byte ^= (key&7)<<4
    __shared__ bf16_t Vt[64 * 64];      // [dim][key], unit ^= dim&7
    __shared__ bf16_t Ps[256 * 64];     // [q][key],   unit ^= q&7

    const int t = threadIdx.x;
    const int w = t >> 6, lane = t & 63;   // w in 0..7
    const int r16 = lane & 15, g = lane >> 4;
    const int g4 = g * 4;

    // XCD swizzle (bijective over 512): gid = (kk>>3)*8 + xc, qt = kk&7
    const int flat = blockIdx.x;
    const int xc  = flat & 7;
    const int kk  = flat >> 3;                  // 0..63
    const int gid = ((kk >> 3) << 3) | xc;      // 0..63 = (b,h)
    const int qt  = kk & 7;
    const int b = gid >> 4, h = gid & 15;
    const int q0 = qt * 256;

    // Q fragments: group A rows q0+32w+r16, group B rows +16
    bf16x8 qfA0, qfA1, qfB0, qfB1;
    {
        const bf16_t* qrA = qg + (size_t)(b * SEQ + q0 + 32 * w + r16) * DMODEL + h * DHEAD;
        const bf16_t* qrB = qrA + (size_t)16 * DMODEL;
        qfA0 = *(const bf16x8*)&qrA[g * 8];
        qfA1 = *(const bf16x8*)&qrA[32 + g * 8];
        qfB0 = *(const bf16x8*)&qrB[g * 8];
        qfB1 = *(const bf16x8*)&qrB[32 + g * 8];
    }

    // K staging: 1 gload/thread: dest byte y = w*1024 + lane*16 (8KB buffer)
    const int yk = w * 1024 + lane * 16;
    const int krow = yk >> 7;                       // 0..63
    const int kslot = ((yk >> 4) & 7) ^ (krow & 7); // pre-swizzled source col
    const bf16_t* kbase = kg + (size_t)(b * SEQ + krow) * DMODEL + h * DHEAD + kslot * 8;
    const int kdo = w * 512;                        // elem offset in Ks[b]

    // V staging: key=lane, dims [w*8, w*8+8)  (16B)
    const bf16_t* vbase = vg + (size_t)(b * SEQ + lane) * DMODEL + h * DHEAD + w * 8;

    // K fragment base offsets (elems); key = nj*16 + r16 -> + nj*1024
    const int klin0 = ((r16 * 128 + g * 16) ^ ((r16 & 7) << 4)) >> 1;
    const int klin1 = ((r16 * 128 + 64 + g * 16) ^ ((r16 & 7) << 4)) >> 1;

    const int lu = lane >> 3, l7 = lane & 7;   // V-write unit/offset
    const int qs = r16 & 7;

    const f32x4 z4 = {0.f, 0.f, 0.f, 0.f};
    float l2A = 0.f, l2B = 0.f;        // per-lane denominator partials
    f32x4 oA[4], oB[4];
#pragma unroll
    for (int i = 0; i < 4; ++i) { oA[i] = z4; oB[i] = z4; }

    const float C2 = 0.1803368801f;    // (1/8) * log2(e)
    const float M2 = 17.31234049f;     // 12 * log2(e): fixed softmax shift

    // prologue: stage tile 0 (V load issued after K gload -> FIFO drain)
    gload_lds16(kbase, &Ks[0][kdo]);
    bf16x8 vcur = *(const bf16x8*)vbase;
    bf16x8 vnxt = vcur;

    const int NT = SEQ / 64;           // 32
    for (int it = 0; it < NT; ++it) {
        const int cur = it & 1;
        const int kv0 = it * 64;

        // 1. Vt write (vmcnt wait on vcur drains K(t) gload too)
#pragma unroll
        for (int e = 0; e < 8; ++e)
            Vt[(w * 8 + e) * 64 + (((lu ^ e) << 3) | l7)] = vcur[e];

        // 2. B1
        asm volatile("s_waitcnt lgkmcnt(0)" ::: "memory");
        __builtin_amdgcn_s_barrier();

        // 3. prefetch tile t+1 (stays in flight across compute)
        if (it + 1 < NT) {
            gload_lds16(kbase + (size_t)(kv0 + 64) * DMODEL, &Ks[cur ^ 1][kdo]);
            vnxt = *(const bf16x8*)(vbase + (size_t)(kv0 + 64) * DMODEL);
        }

        // 4. S^T = K Q^T for both q-groups; each kf pair feeds 4 MFMAs
        f32x4 sA[4], sB[4];
        __builtin_amdgcn_s_setprio(1);
#pragma unroll
        for (int nj = 0; nj < 4; ++nj) {
            bf16x8 kf0 = *(const bf16x8*)&Ks[cur][klin0 + nj * 1024];
            bf16x8 kf1 = *(const bf16x8*)&Ks[cur][klin1 + nj * 1024];
            sA[nj] = __builtin_amdgcn_mfma_f32_16x16x32_bf16(kf0, qfA0, z4, 0, 0, 0);
            sA[nj] = __builtin_amdgcn_mfma_f32_16x16x32_bf16(kf1, qfA1, sA[nj], 0, 0, 0);
            sB[nj] = __builtin_amdgcn_mfma_f32_16x16x32_bf16(kf0, qfB0, z4, 0, 0, 0);
            sB[nj] = __builtin_amdgcn_mfma_f32_16x16x32_bf16(kf1, qfB1, sB[nj], 0, 0, 0);
        }
        __builtin_amdgcn_s_setprio(0);

        // 5. exp (fixed shift; no cross-lane, no max tracking)
        float pA[4][4], pB[4][4];
        float rsA = 0.f, rsB = 0.f;
#pragma unroll
        for (int j = 0; j < 4; ++j)
#pragma unroll
            for (int rr = 0; rr < 4; ++rr) {
                pA[j][rr] = __builtin_amdgcn_exp2f(sA[j][rr] * C2 - M2);
                rsA += pA[j][rr];
                pB[j][rr] = __builtin_amdgcn_exp2f(sB[j][rr] * C2 - M2);
                rsB += pB[j][rr];
            }
        l2A += rsA;
        l2B += rsB;

        // 6. Ps pack (wave-local rows) + lgkm wait + read A-frags
        const int qrA = 32 * w + r16;
        const int qrB = qrA + 16;
#pragma unroll
        for (int j = 0; j < 4; ++j) {
            bf16x4 pkA, pkB;
            pkA[0] = (bf16_t)pA[j][0]; pkA[1] = (bf16_t)pA[j][1];
            pkA[2] = (bf16_t)pA[j][2]; pkA[3] = (bf16_t)pA[j][3];
            pkB[0] = (bf16_t)pB[j][0]; pkB[1] = (bf16_t)pB[j][1];
            pkB[2] = (bf16_t)pB[j][2]; pkB[3] = (bf16_t)pB[j][3];
            const int u = ((((2 * j + (g >> 1)) ^ qs) << 3) | ((g & 1) << 2));
            *(bf16x4*)&Ps[qrA * 64 + u] = pkA;
            *(bf16x4*)&Ps[qrB * 64 + u] = pkB;
        }
        asm volatile("s_waitcnt lgkmcnt(0)" ::: "memory");
        bf16x8 pfA0 = *(const bf16x8*)&Ps[qrA * 64 + ((g ^ qs) << 3)];
        bf16x8 pfA1 = *(const bf16x8*)&Ps[qrA * 64 + (((4 + g) ^ qs) << 3)];
        bf16x8 pfB0 = *(const bf16x8*)&Ps[qrB * 64 + ((g ^ qs) << 3)];
        bf16x8 pfB1 = *(const bf16x8*)&Ps[qrB * 64 + (((4 + g) ^ qs) << 3)];

        // 7. O += P V : vf reads shared by both q-groups
        __builtin_amdgcn_s_setprio(1);
#pragma unroll
        for (int dj = 0; dj < 4; ++dj) {
            const int d = dj * 16 + r16;
            bf16x8 vf0 = *(const bf16x8*)&Vt[d * 64 + ((g ^ qs) << 3)];
            bf16x8 vf1 = *(const bf16x8*)&Vt[d * 64 + (((4 + g) ^ qs) << 3)];
            oA[dj] = __builtin_amdgcn_mfma_f32_16x16x32_bf16(pfA0, vf0, oA[dj], 0, 0, 0);
            oA[dj] = __builtin_amdgcn_mfma_f32_16x16x32_bf16(pfA1, vf1, oA[dj], 0, 0, 0);
            oB[dj] = __builtin_amdgcn_mfma_f32_16x16x32_bf16(pfB0, vf0, oB[dj], 0, 0, 0);
            oB[dj] = __builtin_amdgcn_mfma_f32_16x16x32_bf16(pfB1, vf1, oB[dj], 0, 0, 0);
        }
        __builtin_amdgcn_s_setprio(0);

        // 8. B2 (raw barrier; vmem prefetch stays in flight)
        asm volatile("s_waitcnt lgkmcnt(0)" ::: "memory");
        __builtin_amdgcn_s_barrier();

        vcur = vnxt;
    }

    // final denominators: sum the 4 g-lane partials of each q-row (once)
    l2A += __shfl_xor(l2A, 16);
    l2A += __shfl_xor(l2A, 32);
    l2B += __shfl_xor(l2B, 16);
    l2B += __shfl_xor(l2B, 32);

    // write context (bf16): oA rows q = 32w+g4+rr, oB rows +16
#pragma unroll
    for (int rr = 0; rr < 4; ++rr) {
        const float invA = 1.0f / __shfl(l2A, g4 + rr, 16);
        const float invB = 1.0f / __shfl(l2B, g4 + rr, 16);
        const size_t rbA =
            (size_t)(b * SEQ + q0 + 32 * w + g4 + rr) * DMODEL + h * DHEAD;
        const size_t rbB = rbA + (size_t)16 * DMODEL;
#pragma unroll
        for (int dj = 0; dj < 4; ++dj) {
            ctx[rbA + dj * 16 + r16] = (bf16_t)(oA[dj][rr] * invA);
            ctx[rbB + dj * 16 + r16] = (bf16_t)(oB[dj][rr] * invB);
        }
    }
}

// ---------------------------------------------------------------------------
// out = LayerNorm(x + res) * g + b, rows of 1024. x is bf16, res fp32.
// ---------------------------------------------------------------------------
__global__ __launch_bounds__(256) void ln_residual(
    const bf16_t* __restrict__ x, const float* __restrict__ res,
    const float* __restrict__ g, const float* __restrict__ bb,
    float* __restrict__ out)
{
    const int row = blockIdx.x;
    const int t = threadIdx.x;
    bf16x4 xv = *(const bf16x4*)&x[(size_t)row * DMODEL + t * 4];
    f4 rv = *(const f4*)&res[(size_t)row * DMODEL + t * 4];
    f4 v;
#pragma unroll
    for (int u = 0; u < 4; ++u) v[u] = (float)xv[u] + rv[u];

    float s = 0.f, s2 = 0.f;
#pragma unroll
    for (int u = 0; u < 4; ++u) { s += v[u]; s2 += v[u] * v[u]; }
#pragma unroll
    for (int off = 1; off < 64; off <<= 1) {
        s  += __shfl_xor(s, off);
        s2 += __shfl_xor(s2, off);
    }
    __shared__ float red[2][4];
    const int wid = t >> 6, lane = t & 63;
    if (lane == 0) { red[0][wid] = s; red[1][wid] = s2; }
    __syncthreads();
    s  = red[0][0] + red[0][1] + red[0][2] + red[0][3];
    s2 = red[1][0] + red[1][1] + red[1][2] + red[1][3];

    const float mean = s * (1.0f / DMODEL);
    const float var  = s2 * (1.0f / DMODEL) - mean * mean;
    const float rstd = rsqrtf(var + LN_EPS);

    f4 gv = *(const f4*)&g[t * 4];
    f4 bv = *(const f4*)&bb[t * 4];
    f4 ov;
#pragma unroll
    for (int u = 0; u < 4; ++u) ov[u] = (v[u] - mean) * rstd * gv[u] + bv[u];
    *(f4*)&out[(size_t)row * DMODEL + t * 4] = ov;
}

// ---------------------------------------------------------------------------
extern "C" void kernel_launch(void* const* d_in, const int* in_sizes, int n_in,
                              void* d_out, int out_size, void* d_ws, size_t ws_size,
                              hipStream_t stream)
{
    const float* Q   = (const float*)d_in[0];
    const float* Wq  = (const float*)d_in[1];
    const float* bq  = (const float*)d_in[2];
    const float* Wk  = (const float*)d_in[3];
    const float* bk  = (const float*)d_in[4];
    const float* Wv  = (const float*)d_in[5];
    const float* bv  = (const float*)d_in[6];
    const float* Wo  = (const float*)d_in[7];
    const float* bo  = (const float*)d_in[8];
    const float* lng = (const float*)d_in[9];
    const float* lnb = (const float*)d_in[10];

    char* wsb = (char*)d_ws;
    // 0..16M: Qbf | 16..32M: q/ctx | 32..48M: k | 48..64M: v (q,k,v contiguous)
    // 32..48M (after attn): attn_out bf16 | 64..72M: Wqt|Wkt|Wvt|Wot contiguous
    bf16_t* Qbf  = (bf16_t*)(wsb);
    bf16_t* qb   = (bf16_t*)(wsb + (size_t)(16 << 20));
    bf16_t* kb   = (bf16_t*)(wsb + (size_t)(32 << 20));
    bf16_t* vbuf = (bf16_t*)(wsb + (size_t)(48 << 20));
    bf16_t* aob  = (bf16_t*)(wsb + (size_t)(32 << 20));
    bf16_t* Wqt  = (bf16_t*)(wsb + (size_t)(64 << 20));   // [3072][1024] fused
    bf16_t* Wot  = (bf16_t*)(wsb + (size_t)(70 << 20));

    cvt_bf16<<<2048, 256, 0, stream>>>(Q, Qbf, MTOT * DMODEL / 4);
    wtrans4<<<dim3(32, 32, 4), 256, 0, stream>>>(Wq, Wk, Wv, Wo, Wqt);

    // fused QKV projection: N=3072, outputs qb|kb|vbuf (contiguous)
    gemm_mfma<1, 1><<<24 * 64, 256, 0, stream>>>(Qbf, Wqt, bq, bk, bv, qb);

    const int agrid = (SEQ / 256) * NHEAD * BATCH;     // 512, XCD-swizzled
    flash_mfma<<<agrid, 512, 0, stream>>>(qb, kb, vbuf, qb);  // ctx aliases q

    gemm_mfma<1, 0><<<8 * 64, 256, 0, stream>>>(qb, Wot, bo, bo, bo, aob);

    ln_residual<<<MTOT, 256, 0, stream>>>(aob, Q, lng, lnb, (float*)d_out);
}